// Round 3
// baseline (593.569 us; speedup 1.0000x reference)
//
#include <hip/hip_runtime.h>
#include <math.h>

#define N_BATCH 8
#define WDIM 64
#define TDIM 8192
#define KBINS 2048
#define NROWS (N_BATCH * TDIM)          // 65536
#define CHUNK 128
#define NCHUNKS (KBINS / CHUNK)         // 16
#define RPB 64                          // rows per block
#define XSIZE (N_BATCH * WDIM * TDIM)   // 4194304
#define XL_OFF 0
#define XD_OFF NROWS
#define SCAL_OFF (NROWS + XSIZE)
#define TAU 0.125f                      // ~600x both impls' fp32 noise
#define MAXFLAG 16384

// ws layout (bytes):
//   0    : double wsd[4]  (sum, sumsq, commit, fit)
//   64   : float  k2[KBINS]   (np-bit-exact pairwise sum of k*k)
//   8320 : int    flag_cnt
//   8384 : int    flags[MAXFLAG]
#define WS_K2_OFF   64
#define WS_CNT_OFF  8320
#define WS_FLAG_OFF 8384

__global__ void init_ws(double* wsd, int* cnt) {
  if (threadIdx.x < 4) wsd[threadIdx.x] = 0.0;
  if (threadIdx.x == 4) *cnt = 0;
}

// k2[j] = numpy-pairwise-exact sum of k[j,:]^2 (n=64 scalar path:
// 8 accumulators over stride-8 blocks, then pairwise combine).
__global__ void knorm_np(const float* __restrict__ k, float* __restrict__ k2) {
  int j = blockIdx.x * blockDim.x + threadIdx.x;
  if (j >= KBINS) return;
  const float* kr = k + j * WDIM;
  float r[8];
#pragma unroll
  for (int l = 0; l < 8; ++l) r[l] = __fmul_rn(kr[l], kr[l]);
  for (int i = 8; i < WDIM; i += 8) {
#pragma unroll
    for (int l = 0; l < 8; ++l) {
      float v = kr[i + l];
      r[l] = __fadd_rn(r[l], __fmul_rn(v, v));
    }
  }
  k2[j] = __fadd_rn(__fadd_rn(__fadd_rn(r[0], r[1]), __fadd_rn(r[2], r[3])),
                    __fadd_rn(__fadd_rn(r[4], r[5]), __fadd_rn(r[6], r[7])));
}

// block = 256 threads = 64 rows x 4 code-quarters.
__launch_bounds__(256, 4)
__global__ void vq_main(const float* __restrict__ x,
                        const float* __restrict__ k,
                        const float* __restrict__ k2g,
                        float* __restrict__ out,
                        double* __restrict__ wsd,
                        int* __restrict__ flag_cnt,
                        int* __restrict__ flags) {
  __shared__ float sk[CHUNK * WDIM];   // 32 KB code chunk
  __shared__ float sk2[CHUNK];
  __shared__ float rd[256];
  __shared__ float r2[256];
  __shared__ int   ri[256];

  const int tid = threadIdx.x;
  const int r   = tid & 63;
  const int q   = tid >> 6;            // code quarter (wave-uniform)
  const int row = blockIdx.x * RPB + r;
  const int n   = row >> 13;
  const int t   = row & (TDIM - 1);

  float xv[WDIM];
  const float* xb = x + n * (WDIM * TDIM) + t;
#pragma unroll
  for (int w = 0; w < WDIM; ++w) xv[w] = xb[w * TDIM];

  float x2 = 0.f;
#pragma unroll
  for (int w = 0; w < WDIM; ++w) x2 = fmaf(xv[w], xv[w], x2);

  float bestd = 3.4e38f;               // tracks (k2 - 2*dot); +x2 at the end
  float best2 = 3.4e38f;               // second-best (for tie flagging)
  int   besti = 0;

  for (int c = 0; c < NCHUNKS; ++c) {
    __syncthreads();
    {
      const float4* kg4 = (const float4*)(k + c * CHUNK * WDIM);
      float4* sk4 = (float4*)sk;
#pragma unroll
      for (int i = 0; i < (CHUNK * WDIM / 4) / 256; ++i)
        sk4[tid + i * 256] = kg4[tid + i * 256];
      if (tid < CHUNK) sk2[tid] = k2g[c * CHUNK + tid];
    }
    __syncthreads();

    const int jbase = q * (CHUNK / 4);
#pragma unroll 2
    for (int jj = 0; jj < CHUNK / 4; ++jj) {
      const int jl = jbase + jj;
      const float4* kp = (const float4*)(sk + jl * WDIM);  // wave-uniform -> broadcast
      float d0 = 0.f, d1 = 0.f, d2 = 0.f, d3 = 0.f;
#pragma unroll
      for (int w4 = 0; w4 < WDIM / 4; ++w4) {
        float4 kv = kp[w4];
        d0 = fmaf(xv[4 * w4 + 0], kv.x, d0);
        d1 = fmaf(xv[4 * w4 + 1], kv.y, d1);
        d2 = fmaf(xv[4 * w4 + 2], kv.z, d2);
        d3 = fmaf(xv[4 * w4 + 3], kv.w, d3);
      }
      float dot = (d0 + d1) + (d2 + d3);
      float d = fmaf(-2.f, dot, sk2[jl]);
      int jg = c * CHUNK + jl;
      if (d < bestd) { best2 = bestd; bestd = d; besti = jg; }
      else           { best2 = fminf(best2, d); }
    }
  }

  rd[tid] = bestd;
  r2[tid] = best2;
  ri[tid] = besti;
  __syncthreads();

  if (tid < 64) {   // wave 0 epilogue; owns row = blk*64 + tid
    float bd = rd[tid];
    float b2 = r2[tid];
    int   bi = ri[tid];
#pragma unroll
    for (int qq = 1; qq < 4; ++qq) {
      float dv = rd[qq * 64 + tid];
      float s2 = r2[qq * 64 + tid];
      int   iv = ri[qq * 64 + tid];
      float nb2 = fminf(fminf(b2, s2), fmaxf(bd, dv));
      if (dv < bd || (dv == bd && iv < bi)) { bd = dv; bi = iv; }
      b2 = nb2;
    }

    out[XL_OFF + row] = (float)bi;

    if (b2 - bd < TAU) {           // near-tie: np-bit-exact recheck later
      int slot = atomicAdd(flag_cnt, 1);
      if (slot < MAXFLAG) flags[slot] = row;
    }

    float commit = 0.f;
    const float4* kb = (const float4*)(k + bi * WDIM);
    float* xd = out + XD_OFF + n * (WDIM * TDIM) + t;
#pragma unroll
    for (int w4 = 0; w4 < WDIM / 4; ++w4) {
      float4 kv = kb[w4];
      xd[(4 * w4 + 0) * TDIM] = kv.x;
      xd[(4 * w4 + 1) * TDIM] = kv.y;
      xd[(4 * w4 + 2) * TDIM] = kv.z;
      xd[(4 * w4 + 3) * TDIM] = kv.w;
      float e0 = kv.x - xv[4 * w4 + 0]; commit = fmaf(e0, e0, commit);
      float e1 = kv.y - xv[4 * w4 + 1]; commit = fmaf(e1, e1, commit);
      float e2 = kv.z - xv[4 * w4 + 2]; commit = fmaf(e2, e2, commit);
      float e3 = kv.w - xv[4 * w4 + 3]; commit = fmaf(e3, e3, commit);
    }

    float fitv = bd + x2;
    float sumx = 0.f;
#pragma unroll
    for (int w = 0; w < WDIM; ++w) sumx += xv[w];
    float sq = x2;

#pragma unroll
    for (int off = 32; off > 0; off >>= 1) {
      fitv   += __shfl_down(fitv,   off, 64);
      commit += __shfl_down(commit, off, 64);
      sumx   += __shfl_down(sumx,   off, 64);
      sq     += __shfl_down(sq,     off, 64);
    }
    if (tid == 0) {
      atomicAdd(&wsd[0], (double)sumx);
      atomicAdd(&wsd[1], (double)sq);
      atomicAdd(&wsd[2], (double)commit);
      atomicAdd(&wsd[3], (double)fitv);
    }
  }
}

// numpy-bit-exact fp32 re-scan of flagged rows:
//   x2  : numpy scalar pairwise sum (8-accumulator scheme)
//   dot : sequential fp32 FMA chain over w ascending (BLAS microkernel order)
//   dist: fl(fl(x2 - 2*dot) + k2), argmin first-occurrence.
__global__ void recheck_np(const float* __restrict__ x,
                           const float* __restrict__ k,
                           const float* __restrict__ k2g,
                           const int* __restrict__ flag_cnt,
                           const int* __restrict__ flags,
                           float* __restrict__ out) {
  __shared__ float sx[WDIM];
  __shared__ float sx2;
  __shared__ float sd[256];
  __shared__ int   si[256];
  __shared__ int   s_best;

  const int tid = threadIdx.x;
  int nf = *flag_cnt;
  if (nf > MAXFLAG) nf = MAXFLAG;

  for (int fi = blockIdx.x; fi < nf; fi += gridDim.x) {
    const int row = flags[fi];
    const int n = row >> 13;
    const int t = row & (TDIM - 1);
    if (tid < WDIM) sx[tid] = x[n * (WDIM * TDIM) + tid * TDIM + t];
    __syncthreads();

    if (tid == 0) {
      float r[8];
#pragma unroll
      for (int l = 0; l < 8; ++l) r[l] = __fmul_rn(sx[l], sx[l]);
      for (int i = 8; i < WDIM; i += 8) {
#pragma unroll
        for (int l = 0; l < 8; ++l)
          r[l] = __fadd_rn(r[l], __fmul_rn(sx[i + l], sx[i + l]));
      }
      sx2 = __fadd_rn(__fadd_rn(__fadd_rn(r[0], r[1]), __fadd_rn(r[2], r[3])),
                      __fadd_rn(__fadd_rn(r[4], r[5]), __fadd_rn(r[6], r[7])));
    }
    __syncthreads();
    const float x2 = sx2;

    float bd = 3.4e38f;
    int   bi = KBINS;
    for (int j = tid; j < KBINS; j += 256) {   // ascending per thread
      const float* kr = k + j * WDIM;
      float c = 0.f;
#pragma unroll
      for (int w = 0; w < WDIM; ++w)
        c = __fmaf_rn(sx[w], kr[w], c);
      float d = __fadd_rn(__fsub_rn(x2, __fmul_rn(2.0f, c)), k2g[j]);
      if (d < bd) { bd = d; bi = j; }
    }
    sd[tid] = bd;
    si[tid] = bi;
    __syncthreads();

    for (int off = 128; off > 0; off >>= 1) {
      if (tid < off) {
        float od = sd[tid + off];
        int   oi = si[tid + off];
        if (od < sd[tid] || (od == sd[tid] && oi < si[tid])) {
          sd[tid] = od;
          si[tid] = oi;
        }
      }
      __syncthreads();
    }
    if (tid == 0) {
      s_best = si[0];
      out[XL_OFF + row] = (float)si[0];
    }
    __syncthreads();
    const int bj = s_best;
    if (tid < WDIM)
      out[XD_OFF + n * (WDIM * TDIM) + tid * TDIM + t] = k[bj * WDIM + tid];
    __syncthreads();
  }
}

__global__ void finalize_kernel(const double* __restrict__ wsd, float* __restrict__ out) {
  if (threadIdx.x == 0) {
    double size = (double)XSIZE;
    double commit = wsd[2] / size;
    double fit = wsd[3] / (double)NROWS;
    double mean = wsd[0] / size;
    double var = wsd[1] / size - mean * mean;
    if (var < 0.0) var = 0.0;
    out[SCAL_OFF + 0] = (float)commit;
    out[SCAL_OFF + 1] = (float)fit;
    out[SCAL_OFF + 2] = (float)sqrt(var);
  }
}

extern "C" void kernel_launch(void* const* d_in, const int* in_sizes, int n_in,
                              void* d_out, int out_size, void* d_ws, size_t ws_size,
                              hipStream_t stream) {
  const float* x = (const float*)d_in[0];
  const float* k = (const float*)d_in[1];
  float* out = (float*)d_out;
  double* wsd = (double*)d_ws;
  float* k2   = (float*)((char*)d_ws + WS_K2_OFF);
  int* cnt    = (int*)((char*)d_ws + WS_CNT_OFF);
  int* flags  = (int*)((char*)d_ws + WS_FLAG_OFF);

  hipLaunchKernelGGL(init_ws, dim3(1), dim3(64), 0, stream, wsd, cnt);
  hipLaunchKernelGGL(knorm_np, dim3(KBINS / 256), dim3(256), 0, stream, k, k2);
  hipLaunchKernelGGL(vq_main, dim3(NROWS / RPB), dim3(256), 0, stream,
                     x, k, k2, out, wsd, cnt, flags);
  hipLaunchKernelGGL(recheck_np, dim3(256), dim3(256), 0, stream,
                     x, k, k2, cnt, flags, out);
  hipLaunchKernelGGL(finalize_kernel, dim3(1), dim3(1), 0, stream, wsd, out);
}

// Round 4
// 421.924 us; speedup vs baseline: 1.4068x; 1.4068x over previous
//
#include <hip/hip_runtime.h>
#include <hip/hip_bf16.h>
#include <math.h>

#define N_BATCH 8
#define WDIM 64
#define TDIM 8192
#define KBINS 2048
#define NROWS (N_BATCH * TDIM)          // 65536
#define XSIZE (N_BATCH * WDIM * TDIM)   // 4194304
#define XL_OFF 0
#define XD_OFF NROWS
#define SCAL_OFF (NROWS + XSIZE)

#define MT 128                          // rows per block (vq)
#define CN 256                          // codes per LDS chunk (vq)
#define NCH (KBINS / CN)                // 8
#define KST 72                          // bf16 LDS row stride (pad 64+8)
#define TAU 0.5f                        // >=29 sigma of bf16 dot noise
#define MAXFLAG 16384
#define RCHUNK 128                      // codes per LDS chunk (recheck)

// ws layout (bytes):
//   0    : double wsd[4]  (sum, sumsq, commit, fit)
//   64   : float  k2[KBINS]   (np-bit-exact pairwise sum of k*k)
//   8320 : int    flag_cnt
//   8384 : int    flags[MAXFLAG]
#define WS_K2_OFF   64
#define WS_CNT_OFF  8320
#define WS_FLAG_OFF 8384

typedef __attribute__((ext_vector_type(8))) short bf16x8;
typedef __attribute__((ext_vector_type(4))) float f32x4;

static __device__ __forceinline__ short f2bf(float v) {
  __hip_bfloat16 b = __float2bfloat16(v);
  return *reinterpret_cast<short*>(&b);
}

// prep: init ws + np-bit-exact k2 (numpy n=64 scalar pairwise: 8 accumulators)
__global__ void prep_kernel(const float* __restrict__ kg, float* __restrict__ k2,
                            double* __restrict__ wsd, int* __restrict__ cnt) {
  if (blockIdx.x == 0) {
    if (threadIdx.x < 4) wsd[threadIdx.x] = 0.0;
    if (threadIdx.x == 4) *cnt = 0;
  }
  int j = blockIdx.x * 256 + threadIdx.x;
  if (j >= KBINS) return;
  const float* kr = kg + j * WDIM;
  float r[8];
#pragma unroll
  for (int l = 0; l < 8; ++l) r[l] = __fmul_rn(kr[l], kr[l]);
  for (int i = 8; i < WDIM; i += 8) {
#pragma unroll
    for (int l = 0; l < 8; ++l)
      r[l] = __fadd_rn(r[l], __fmul_rn(kr[i + l], kr[i + l]));
  }
  k2[j] = __fadd_rn(__fadd_rn(__fadd_rn(r[0], r[1]), __fadd_rn(r[2], r[3])),
                    __fadd_rn(__fadd_rn(r[4], r[5]), __fadd_rn(r[6], r[7])));
}

// main: bf16 MFMA distance scan. 128 rows/block, 4 waves x 32 rows (2 subtiles).
__launch_bounds__(256, 2)
__global__ void vq_mfma(const float* __restrict__ x,
                        const float* __restrict__ kg,
                        const float* __restrict__ k2g,
                        float* __restrict__ out,
                        double* __restrict__ wsd,
                        int* __restrict__ flag_cnt,
                        int* __restrict__ flags) {
  __shared__ __align__(16) char smem[58368];
  short* skb  = (short*)smem;              // 36864 B : bf16 k-chunk [CN][KST]
  short* sxa  = (short*)(smem + 36864);    // 18432 B : bf16 x-tile  [MT][KST]
  float* sk2  = (float*)(smem + 55296);    // 1024  B : k2 chunk
  float* sx2  = (float*)(smem + 56320);    // 512   B : per-row x2 (fp32)
  float* sPair= (float*)(smem + 56832);    // 1024  B : x2 partial pairs
  int*   sIdx = (int*)  (smem + 57856);    // 512   B : chosen code per row

  const int tid  = threadIdx.x;
  const int blk  = blockIdx.x;
  const int row0 = blk * MT;
  const int n    = row0 >> 13;
  const int t0   = row0 & (TDIM - 1);

  // ---- stage x tile -> bf16 sxa; accumulate fp32 x2/sum partials ----
  const int r  = tid & 127;
  const int wh = tid >> 7;                 // w parity
  float x2p = 0.f, sxp = 0.f;
  const float* xb = x + (size_t)n * WDIM * TDIM + t0 + r;
  for (int i = 0; i < 32; ++i) {
    int w = 2 * i + wh;
    float v = xb[(size_t)w * TDIM];
    x2p = fmaf(v, v, x2p);
    sxp += v;
    sxa[r * KST + w] = f2bf(v);
  }
  sPair[tid] = x2p;
  __syncthreads();
  if (tid < MT) sx2[tid] = sPair[tid] + sPair[tid + 128];
  __syncthreads();

  // ---- A fragments (held in registers for the whole sweep) ----
  const int wave = tid >> 6;
  const int lane = tid & 63;
  const int lcol = lane & 15;              // MFMA m/n index
  const int quad = lane >> 4;              // MFMA k-quad
  const int rA0 = wave * 32 + lcol;        // subtile 0 row
  const int rA1 = wave * 32 + 16 + lcol;   // subtile 1 row
  bf16x8 a0h0 = *(const bf16x8*)&sxa[rA0 * KST + 0  + quad * 8];
  bf16x8 a0h1 = *(const bf16x8*)&sxa[rA0 * KST + 32 + quad * 8];
  bf16x8 a1h0 = *(const bf16x8*)&sxa[rA1 * KST + 0  + quad * 8];
  bf16x8 a1h1 = *(const bf16x8*)&sxa[rA1 * KST + 32 + quad * 8];

  float bd[8], b2[8];
  int   bi[8];
#pragma unroll
  for (int i = 0; i < 8; ++i) { bd[i] = 3.0e38f; b2[i] = 3.0e38f; bi[i] = 0; }

  // ---- sweep codes in chunks of CN ----
  for (int c = 0; c < NCH; ++c) {
    __syncthreads();
    {
      const float4* kg4 = (const float4*)(kg + (size_t)c * CN * WDIM);
#pragma unroll
      for (int i = 0; i < (CN * WDIM / 4) / 256; ++i) {   // 16 iters
        float4 kv = kg4[tid + i * 256];
        int idx4 = (tid + i * 256) * 4;
        int code = idx4 >> 6, w = idx4 & 63;
        short4 pk = make_short4(f2bf(kv.x), f2bf(kv.y), f2bf(kv.z), f2bf(kv.w));
        *(short4*)&skb[code * KST + w] = pk;
      }
      if (tid < CN) sk2[tid] = k2g[c * CN + tid];
    }
    __syncthreads();

    const int cbase = c * CN;
#pragma unroll 2
    for (int ct = 0; ct < CN / 16; ++ct) {               // 16 code-tiles
      const int cb = ct * 16;
      bf16x8 b0 = *(const bf16x8*)&skb[(cb + lcol) * KST + 0  + quad * 8];
      bf16x8 b1 = *(const bf16x8*)&skb[(cb + lcol) * KST + 32 + quad * 8];
      float k2c = sk2[cb + lcol];
      f32x4 acc0 = {0.f, 0.f, 0.f, 0.f};
      f32x4 acc1 = {0.f, 0.f, 0.f, 0.f};
      acc0 = __builtin_amdgcn_mfma_f32_16x16x32_bf16(a0h0, b0, acc0, 0, 0, 0);
      acc1 = __builtin_amdgcn_mfma_f32_16x16x32_bf16(a1h0, b0, acc1, 0, 0, 0);
      acc0 = __builtin_amdgcn_mfma_f32_16x16x32_bf16(a0h1, b1, acc0, 0, 0, 0);
      acc1 = __builtin_amdgcn_mfma_f32_16x16x32_bf16(a1h1, b1, acc1, 0, 0, 0);
      const int code = cbase + cb + lcol;
#pragma unroll
      for (int i = 0; i < 4; ++i) {
        float d0 = fmaf(-2.f, acc0[i], k2c);
        float nb2a = fminf(b2[i], fmaxf(bd[i], d0));
        bool lt0 = d0 < bd[i];
        bd[i] = lt0 ? d0 : bd[i];
        bi[i] = lt0 ? code : bi[i];
        b2[i] = nb2a;
        float d1 = fmaf(-2.f, acc1[i], k2c);
        float nb2b = fminf(b2[4 + i], fmaxf(bd[4 + i], d1));
        bool lt1 = d1 < bd[4 + i];
        bd[4 + i] = lt1 ? d1 : bd[4 + i];
        bi[4 + i] = lt1 ? code : bi[4 + i];
        b2[4 + i] = nb2b;
      }
    }
  }

  // ---- reduce across the 16 col-classes (lanes differing in low 4 bits) ----
#pragma unroll
  for (int m = 1; m < 16; m <<= 1) {
#pragma unroll
    for (int i = 0; i < 8; ++i) {
      float od  = __shfl_xor(bd[i], m, 64);
      float od2 = __shfl_xor(b2[i], m, 64);
      int   oi  = __shfl_xor(bi[i], m, 64);
      float nb2 = fminf(fminf(b2[i], od2), fmaxf(bd[i], od));
      bool take = (od < bd[i]) || (od == bd[i] && oi < bi[i]);
      bd[i] = take ? od : bd[i];
      bi[i] = take ? oi : bi[i];
      b2[i] = nb2;
    }
  }

  float fit_p = 0.f;
  if (lcol == 0) {
#pragma unroll
    for (int i = 0; i < 8; ++i) {
      int s = i >> 2, ii = i & 3;
      int rloc = wave * 32 + s * 16 + quad * 4 + ii;
      int rowg = row0 + rloc;
      out[XL_OFF + rowg] = (float)bi[i];
      sIdx[rloc] = bi[i];
      fit_p += bd[i] + sx2[rloc];
      if (b2[i] - bd[i] < TAU) {
        int slot = atomicAdd(flag_cnt, 1);
        if (slot < MAXFLAG) flags[slot] = rowg;
      }
    }
  }
  __syncthreads();

  // ---- gather chosen code rows (fp32) into LDS (reuse skb) ----
  float* kd = (float*)skb;                  // [MT][68] fp32 = 34816 B
  {
    int rr = tid >> 1, half = tid & 1;
    const float4* kr4 = (const float4*)(kg + (size_t)sIdx[rr] * WDIM + half * 32);
    float4* dst = (float4*)&kd[rr * 68 + half * 32];
#pragma unroll
    for (int j = 0; j < 8; ++j) dst[j] = kr4[j];
  }
  __syncthreads();

  // ---- x_d transposed write + commit ----
  float commit_p = 0.f;
  float* xdb = out + XD_OFF + (size_t)n * WDIM * TDIM + t0 + r;
  for (int i = 0; i < 32; ++i) {
    int w = 2 * i + wh;
    float xvv = xb[(size_t)w * TDIM];
    float kvv = kd[r * 68 + w];
    float df = kvv - xvv;
    commit_p = fmaf(df, df, commit_p);
    xdb[(size_t)w * TDIM] = kvv;
  }

  // ---- block scalar reduction -> global atomics ----
  float v0 = sxp, v1 = x2p, v2 = commit_p, v3 = fit_p;
#pragma unroll
  for (int off = 32; off > 0; off >>= 1) {
    v0 += __shfl_down(v0, off, 64);
    v1 += __shfl_down(v1, off, 64);
    v2 += __shfl_down(v2, off, 64);
    v3 += __shfl_down(v3, off, 64);
  }
  if (lane == 0) {
    atomicAdd(&wsd[0], (double)v0);
    atomicAdd(&wsd[1], (double)v1);
    atomicAdd(&wsd[2], (double)v2);
    atomicAdd(&wsd[3], (double)v3);
  }
}

// numpy-bit-exact fp32 re-scan of flagged rows (LDS-staged k chunks).
__launch_bounds__(256, 4)
__global__ void recheck_np(const float* __restrict__ x,
                           const float* __restrict__ kg,
                           const float* __restrict__ k2g,
                           const int* __restrict__ flag_cnt,
                           const int* __restrict__ flags,
                           float* __restrict__ out) {
  __shared__ __align__(16) float skc[RCHUNK * 66];   // 33792 B
  __shared__ float sxr[16 * 65];                     // 4160 B
  __shared__ float sk2c[RCHUNK];
  __shared__ float sx2r[16];
  __shared__ int   sRows[16];
  __shared__ float sWd[4];
  __shared__ int   sWi[4];
  __shared__ int   sWin[16];

  const int tid = threadIdx.x;
  const int blk = blockIdx.x;
  int nf = *flag_cnt;
  if (nf > MAXFLAG) nf = MAXFLAG;

  if (tid < 16) {
    int fi = blk + tid * 1024;
    sRows[tid] = (fi < nf) ? flags[fi] : -1;
  }
  __syncthreads();
  int m = 0;
  while (m < 16 && sRows[m] >= 0) ++m;
  if (m == 0) return;

  // stage flagged rows' x
  for (int lb = 0; lb < 16; lb += 4) {
    int l = lb + (tid >> 6);
    if (l < m) {
      int row = sRows[l];
      int n2 = row >> 13, t2 = row & (TDIM - 1);
      int w = tid & 63;
      sxr[l * 65 + w] = x[(size_t)n2 * WDIM * TDIM + (size_t)w * TDIM + t2];
    }
  }
  __syncthreads();
  if (tid < m) {   // np-pairwise x2
    const float* sxx = &sxr[tid * 65];
    float r8[8];
#pragma unroll
    for (int l = 0; l < 8; ++l) r8[l] = __fmul_rn(sxx[l], sxx[l]);
    for (int i = 8; i < WDIM; i += 8) {
#pragma unroll
      for (int l = 0; l < 8; ++l)
        r8[l] = __fadd_rn(r8[l], __fmul_rn(sxx[i + l], sxx[i + l]));
    }
    sx2r[tid] = __fadd_rn(__fadd_rn(__fadd_rn(r8[0], r8[1]), __fadd_rn(r8[2], r8[3])),
                          __fadd_rn(__fadd_rn(r8[4], r8[5]), __fadd_rn(r8[6], r8[7])));
  }

  const int cc   = tid & 127;       // code class
  const int half = tid >> 7;        // row parity
  float bdv[8];
  int   biv[8];
#pragma unroll
  for (int i = 0; i < 8; ++i) { bdv[i] = 3.4e38f; biv[i] = KBINS; }

  for (int c = 0; c < KBINS / RCHUNK; ++c) {   // 16 chunks
    __syncthreads();
    {
      const float2* kg2 = (const float2*)(kg + (size_t)c * RCHUNK * WDIM);
#pragma unroll
      for (int it = 0; it < (RCHUNK * WDIM / 2) / 256; ++it) {  // 16
        float2 kv = kg2[tid + it * 256];
        int o = (tid + it * 256) * 2;
        int code = o >> 6, w = o & 63;
        *(float2*)&skc[code * 66 + w] = kv;
      }
      if (tid < RCHUNK) sk2c[tid] = k2g[c * RCHUNK + tid];
    }
    __syncthreads();
    float k2cc = sk2c[cc];
    const float* kc = &skc[cc * 66];

    for (int li = 0; li < 8; li += 2) {
      int la = half + 2 * li;
      if (la >= m) break;
      int lb2 = half + 2 * (li + 1);
      bool hasB = lb2 < m;
      const float* xa  = &sxr[la * 65];
      const float* xbr = hasB ? &sxr[lb2 * 65] : xa;
      float ca = 0.f, cb = 0.f;
#pragma unroll
      for (int w = 0; w < WDIM; ++w) {
        float kv = kc[w];
        ca = __fmaf_rn(xa[w],  kv, ca);
        cb = __fmaf_rn(xbr[w], kv, cb);
      }
      int code = c * RCHUNK + cc;
      float da = __fadd_rn(__fsub_rn(sx2r[la], __fmul_rn(2.0f, ca)), k2cc);
      if (da < bdv[li]) { bdv[li] = da; biv[li] = code; }
      if (hasB) {
        float db = __fadd_rn(__fsub_rn(sx2r[lb2], __fmul_rn(2.0f, cb)), k2cc);
        if (db < bdv[li + 1]) { bdv[li + 1] = db; biv[li + 1] = code; }
      }
    }
  }
  __syncthreads();

  // per-row winner across the 128 code-classes
  for (int l = 0; l < 16; ++l) {
    if (l >= m) break;
    float d = 3.4e38f; int ii = KBINS;
    if (half == (l & 1)) { int li = (l - (l & 1)) >> 1; d = bdv[li]; ii = biv[li]; }
#pragma unroll
    for (int off = 32; off > 0; off >>= 1) {
      float od = __shfl_down(d, off, 64);
      int   oi = __shfl_down(ii, off, 64);
      if (od < d || (od == d && oi < ii)) { d = od; ii = oi; }
    }
    if ((tid & 63) == 0) { sWd[tid >> 6] = d; sWi[tid >> 6] = ii; }
    __syncthreads();
    if (tid == 0) {
      float bw = sWd[0]; int bwi = sWi[0];
#pragma unroll
      for (int wv = 1; wv < 4; ++wv)
        if (sWd[wv] < bw || (sWd[wv] == bw && sWi[wv] < bwi)) { bw = sWd[wv]; bwi = sWi[wv]; }
      sWin[l] = bwi;
      out[XL_OFF + sRows[l]] = (float)bwi;
    }
    __syncthreads();
  }

  // rewrite x_d for rechecked rows
  for (int lb = 0; lb < 16; lb += 4) {
    int l = lb + (tid >> 6);
    if (l < m) {
      int row = sRows[l], bj = sWin[l];
      int n2 = row >> 13, t2 = row & (TDIM - 1);
      int w = tid & 63;
      out[XD_OFF + (size_t)n2 * WDIM * TDIM + (size_t)w * TDIM + t2] = kg[bj * WDIM + w];
    }
  }
}

__global__ void finalize_kernel(const double* __restrict__ wsd, float* __restrict__ out) {
  if (threadIdx.x == 0) {
    double size = (double)XSIZE;
    double commit = wsd[2] / size;
    double fit = wsd[3] / (double)NROWS;
    double mean = wsd[0] / size;
    double var = wsd[1] / size - mean * mean;
    if (var < 0.0) var = 0.0;
    out[SCAL_OFF + 0] = (float)commit;
    out[SCAL_OFF + 1] = (float)fit;
    out[SCAL_OFF + 2] = (float)sqrt(var);
  }
}

extern "C" void kernel_launch(void* const* d_in, const int* in_sizes, int n_in,
                              void* d_out, int out_size, void* d_ws, size_t ws_size,
                              hipStream_t stream) {
  const float* x = (const float*)d_in[0];
  const float* kg = (const float*)d_in[1];
  float* out = (float*)d_out;
  double* wsd = (double*)d_ws;
  float* k2  = (float*)((char*)d_ws + WS_K2_OFF);
  int* cnt   = (int*)((char*)d_ws + WS_CNT_OFF);
  int* flags = (int*)((char*)d_ws + WS_FLAG_OFF);

  hipLaunchKernelGGL(prep_kernel, dim3(KBINS / 256), dim3(256), 0, stream, kg, k2, wsd, cnt);
  hipLaunchKernelGGL(vq_mfma, dim3(NROWS / MT), dim3(256), 0, stream,
                     x, kg, k2, out, wsd, cnt, flags);
  hipLaunchKernelGGL(recheck_np, dim3(1024), dim3(256), 0, stream,
                     x, kg, k2, cnt, flags, out);
  hipLaunchKernelGGL(finalize_kernel, dim3(1), dim3(1), 0, stream, wsd, out);
}

// Round 5
// 397.842 us; speedup vs baseline: 1.4920x; 1.0605x over previous
//
#include <hip/hip_runtime.h>
#include <hip/hip_bf16.h>
#include <math.h>

#define N_BATCH 8
#define WDIM 64
#define TDIM 8192
#define KBINS 2048
#define NROWS (N_BATCH * TDIM)          // 65536
#define XSIZE (N_BATCH * WDIM * TDIM)   // 4194304
#define XL_OFF 0
#define XD_OFF NROWS
#define SCAL_OFF (NROWS + XSIZE)

#define MT 128                          // rows per block (vq)
#define XST 72                          // bf16 LDS x row stride
#define TAU 0.0625f                     // >=300 sigma of split-bf16 noise
#define MAXFLAG 8192

// ws layout (bytes):
//   0      : double wsd[4]
//   64     : float  k2[KBINS]          (np-bit-exact)
//   8320   : int    flag_cnt
//   8384   : int    flags[MAXFLAG]     (32 KB)
//   41216  : short  khi[KBINS*64]      (256 KB bf16)
//   303360 : short  klo[KBINS*64]      (256 KB bf16 residual)
#define WS_K2_OFF   64
#define WS_CNT_OFF  8320
#define WS_FLAG_OFF 8384
#define WS_KHI_OFF  41216
#define WS_KLO_OFF  303360

typedef __attribute__((ext_vector_type(8))) short bf16x8;
typedef __attribute__((ext_vector_type(4))) float f32x4;

static __device__ __forceinline__ short f2bf(float v) {
  __hip_bfloat16 b = __float2bfloat16(v);
  return *reinterpret_cast<short*>(&b);
}
static __device__ __forceinline__ float bf2f(short s) {
  unsigned int u = ((unsigned int)(unsigned short)s) << 16;
  return __uint_as_float(u);
}

// prep: init ws + np-bit-exact k2 + split-bf16 codebook (khi + klo)
__global__ void prep_kernel(const float* __restrict__ kg, float* __restrict__ k2,
                            short* __restrict__ khi, short* __restrict__ klo,
                            double* __restrict__ wsd, int* __restrict__ cnt) {
  if (blockIdx.x == 0) {
    if (threadIdx.x < 4) wsd[threadIdx.x] = 0.0;
    if (threadIdx.x == 4) *cnt = 0;
  }
  int j = blockIdx.x * 256 + threadIdx.x;
  if (j >= KBINS) return;
  const float* kr = kg + j * WDIM;
  float r[8];
#pragma unroll
  for (int l = 0; l < 8; ++l) r[l] = __fmul_rn(kr[l], kr[l]);
  for (int i = 8; i < WDIM; i += 8) {
#pragma unroll
    for (int l = 0; l < 8; ++l)
      r[l] = __fadd_rn(r[l], __fmul_rn(kr[i + l], kr[i + l]));
  }
  k2[j] = __fadd_rn(__fadd_rn(__fadd_rn(r[0], r[1]), __fadd_rn(r[2], r[3])),
                    __fadd_rn(__fadd_rn(r[4], r[5]), __fadd_rn(r[6], r[7])));
#pragma unroll
  for (int i = 0; i < WDIM; ++i) {
    float v = kr[i];
    short h = f2bf(v);
    khi[j * WDIM + i] = h;
    klo[j * WDIM + i] = f2bf(v - bf2f(h));
  }
}

// main: split-bf16 MFMA distance scan, B-frags direct from global (no sweep barriers).
__launch_bounds__(256, 4)
__global__ void vq_mfma(const float* __restrict__ x,
                        const float* __restrict__ kg,
                        const float* __restrict__ k2g,
                        const short* __restrict__ khi,
                        const short* __restrict__ klo,
                        float* __restrict__ out,
                        double* __restrict__ wsd,
                        int* __restrict__ flag_cnt,
                        int* __restrict__ flags) {
  __shared__ __align__(16) char smem[38912];
  short* sxh  = (short*)smem;              // [MT][XST] bf16 hi      (18432 B)
  short* sxl  = (short*)(smem + 18432);    // [MT][XST] bf16 lo      (18432 B)
  float* sx2  = (float*)(smem + 36864);    // per-row x2 fp32        (512 B)
  float* sPair= (float*)(smem + 37376);    // x2 partials            (1024 B)
  int*   sIdx = (int*)  (smem + 38400);    // chosen code per row    (512 B)
  float* kd   = (float*)smem;              // epilogue: [MT][68] fp32 (34816 B, reuses sxh/sxl)

  const int tid  = threadIdx.x;
  const int row0 = blockIdx.x * MT;
  const int n    = row0 >> 13;
  const int t0   = row0 & (TDIM - 1);

  // ---- stage x tile -> split bf16; fp32 partials ----
  const int r  = tid & 127;
  const int wh = tid >> 7;                 // w parity
  float x2p = 0.f, sxp = 0.f;
  const float* xb = x + (size_t)n * WDIM * TDIM + t0 + r;
#pragma unroll 8
  for (int i = 0; i < 32; ++i) {
    int w = 2 * i + wh;
    float v = xb[(size_t)w * TDIM];
    x2p = fmaf(v, v, x2p);
    sxp += v;
    short h = f2bf(v);
    sxh[r * XST + w] = h;
    sxl[r * XST + w] = f2bf(v - bf2f(h));
  }
  sPair[tid] = x2p;
  __syncthreads();
  if (tid < MT) sx2[tid] = sPair[tid] + sPair[tid + 128];
  __syncthreads();

  // ---- A fragments (registers for the whole sweep) ----
  const int wave = tid >> 6;
  const int lane = tid & 63;
  const int lcol = lane & 15;
  const int quad = lane >> 4;
  const int rA0 = wave * 32 + lcol;
  const int rA1 = wave * 32 + 16 + lcol;
  bf16x8 a0h0 = *(const bf16x8*)&sxh[rA0 * XST + 0  + quad * 8];
  bf16x8 a0h1 = *(const bf16x8*)&sxh[rA0 * XST + 32 + quad * 8];
  bf16x8 a0l0 = *(const bf16x8*)&sxl[rA0 * XST + 0  + quad * 8];
  bf16x8 a0l1 = *(const bf16x8*)&sxl[rA0 * XST + 32 + quad * 8];
  bf16x8 a1h0 = *(const bf16x8*)&sxh[rA1 * XST + 0  + quad * 8];
  bf16x8 a1h1 = *(const bf16x8*)&sxh[rA1 * XST + 32 + quad * 8];
  bf16x8 a1l0 = *(const bf16x8*)&sxl[rA1 * XST + 0  + quad * 8];
  bf16x8 a1l1 = *(const bf16x8*)&sxl[rA1 * XST + 32 + quad * 8];

  float bd[8], b2[8];
  int   bi[8];
#pragma unroll
  for (int i = 0; i < 8; ++i) { bd[i] = 3.0e38f; b2[i] = 3.0e38f; bi[i] = 0; }

  // ---- sweep all codes, 16 per tile, no barriers ----
#pragma unroll 2
  for (int cb = 0; cb < KBINS; cb += 16) {
    const int code = cb + lcol;
    const short* bh = khi + code * WDIM;
    const short* bl = klo + code * WDIM;
    bf16x8 bh0 = *(const bf16x8*)&bh[0  + quad * 8];
    bf16x8 bh1 = *(const bf16x8*)&bh[32 + quad * 8];
    bf16x8 bl0 = *(const bf16x8*)&bl[0  + quad * 8];
    bf16x8 bl1 = *(const bf16x8*)&bl[32 + quad * 8];
    float k2c = k2g[code];
    f32x4 acc0 = {0.f, 0.f, 0.f, 0.f};
    f32x4 acc1 = {0.f, 0.f, 0.f, 0.f};
    acc0 = __builtin_amdgcn_mfma_f32_16x16x32_bf16(a0h0, bh0, acc0, 0, 0, 0);
    acc1 = __builtin_amdgcn_mfma_f32_16x16x32_bf16(a1h0, bh0, acc1, 0, 0, 0);
    acc0 = __builtin_amdgcn_mfma_f32_16x16x32_bf16(a0h1, bh1, acc0, 0, 0, 0);
    acc1 = __builtin_amdgcn_mfma_f32_16x16x32_bf16(a1h1, bh1, acc1, 0, 0, 0);
    acc0 = __builtin_amdgcn_mfma_f32_16x16x32_bf16(a0h0, bl0, acc0, 0, 0, 0);
    acc1 = __builtin_amdgcn_mfma_f32_16x16x32_bf16(a1h0, bl0, acc1, 0, 0, 0);
    acc0 = __builtin_amdgcn_mfma_f32_16x16x32_bf16(a0h1, bl1, acc0, 0, 0, 0);
    acc1 = __builtin_amdgcn_mfma_f32_16x16x32_bf16(a1h1, bl1, acc1, 0, 0, 0);
    acc0 = __builtin_amdgcn_mfma_f32_16x16x32_bf16(a0l0, bh0, acc0, 0, 0, 0);
    acc1 = __builtin_amdgcn_mfma_f32_16x16x32_bf16(a1l0, bh0, acc1, 0, 0, 0);
    acc0 = __builtin_amdgcn_mfma_f32_16x16x32_bf16(a0l1, bh1, acc0, 0, 0, 0);
    acc1 = __builtin_amdgcn_mfma_f32_16x16x32_bf16(a1l1, bh1, acc1, 0, 0, 0);
#pragma unroll
    for (int i = 0; i < 4; ++i) {
      float d0 = fmaf(-2.f, acc0[i], k2c);
      float nb2a = fminf(b2[i], fmaxf(bd[i], d0));
      bool lt0 = d0 < bd[i];
      bd[i] = lt0 ? d0 : bd[i];
      bi[i] = lt0 ? code : bi[i];
      b2[i] = nb2a;
      float d1 = fmaf(-2.f, acc1[i], k2c);
      float nb2b = fminf(b2[4 + i], fmaxf(bd[4 + i], d1));
      bool lt1 = d1 < bd[4 + i];
      bd[4 + i] = lt1 ? d1 : bd[4 + i];
      bi[4 + i] = lt1 ? code : bi[4 + i];
      b2[4 + i] = nb2b;
    }
  }

  // ---- reduce across the 16 col-classes ----
#pragma unroll
  for (int m = 1; m < 16; m <<= 1) {
#pragma unroll
    for (int i = 0; i < 8; ++i) {
      float od  = __shfl_xor(bd[i], m, 64);
      float od2 = __shfl_xor(b2[i], m, 64);
      int   oi  = __shfl_xor(bi[i], m, 64);
      float nb2 = fminf(fminf(b2[i], od2), fmaxf(bd[i], od));
      bool take = (od < bd[i]) || (od == bd[i] && oi < bi[i]);
      bd[i] = take ? od : bd[i];
      bi[i] = take ? oi : bi[i];
      b2[i] = nb2;
    }
  }

  float fit_p = 0.f;
  if (lcol == 0) {
#pragma unroll
    for (int i = 0; i < 8; ++i) {
      int s = i >> 2, ii = i & 3;
      int rloc = wave * 32 + s * 16 + quad * 4 + ii;
      int rowg = row0 + rloc;
      out[XL_OFF + rowg] = (float)bi[i];
      sIdx[rloc] = bi[i];
      fit_p += bd[i] + sx2[rloc];
      if (b2[i] - bd[i] < TAU) {
        int slot = atomicAdd(flag_cnt, 1);
        if (slot < MAXFLAG) flags[slot] = rowg;
      }
    }
  }
  __syncthreads();

  // ---- gather chosen code rows (fp32) into LDS ----
  {
    int rr = tid >> 1, half = tid & 1;
    const float4* kr4 = (const float4*)(kg + (size_t)sIdx[rr] * WDIM + half * 32);
    float4* dst = (float4*)&kd[rr * 68 + half * 32];
#pragma unroll
    for (int j = 0; j < 8; ++j) dst[j] = kr4[j];
  }
  __syncthreads();

  // ---- x_d transposed write + commit ----
  float commit_p = 0.f;
  float* xdb = out + XD_OFF + (size_t)n * WDIM * TDIM + t0 + r;
#pragma unroll 8
  for (int i = 0; i < 32; ++i) {
    int w = 2 * i + wh;
    float xvv = xb[(size_t)w * TDIM];
    float kvv = kd[r * 68 + w];
    float df = kvv - xvv;
    commit_p = fmaf(df, df, commit_p);
    xdb[(size_t)w * TDIM] = kvv;
  }

  // ---- block scalar reduction -> global atomics ----
  float v0 = sxp, v1 = x2p, v2 = commit_p, v3 = fit_p;
#pragma unroll
  for (int off = 32; off > 0; off >>= 1) {
    v0 += __shfl_down(v0, off, 64);
    v1 += __shfl_down(v1, off, 64);
    v2 += __shfl_down(v2, off, 64);
    v3 += __shfl_down(v3, off, 64);
  }
  if (lane == 0) {
    atomicAdd(&wsd[0], (double)v0);
    atomicAdd(&wsd[1], (double)v1);
    atomicAdd(&wsd[2], (double)v2);
    atomicAdd(&wsd[3], (double)v3);
  }
}

// numpy-bit-exact fp32 re-scan: one block per flagged row.
__launch_bounds__(256, 4)
__global__ void recheck_np(const float* __restrict__ x,
                           const float* __restrict__ kg,
                           const float* __restrict__ k2g,
                           const int* __restrict__ flag_cnt,
                           const int* __restrict__ flags,
                           float* __restrict__ out) {
  __shared__ float sx[WDIM];
  __shared__ float sx2s;
  __shared__ float sd[256];
  __shared__ int   si[256];

  const int tid = threadIdx.x;
  int nf = *flag_cnt;
  if (nf > MAXFLAG) nf = MAXFLAG;
  if (blockIdx.x >= nf) return;

  const int row = flags[blockIdx.x];
  const int n = row >> 13;
  const int t = row & (TDIM - 1);
  if (tid < WDIM) sx[tid] = x[(size_t)n * WDIM * TDIM + (size_t)tid * TDIM + t];
  __syncthreads();

  if (tid == 0) {   // np-pairwise x2
    float r8[8];
#pragma unroll
    for (int l = 0; l < 8; ++l) r8[l] = __fmul_rn(sx[l], sx[l]);
    for (int i = 8; i < WDIM; i += 8) {
#pragma unroll
      for (int l = 0; l < 8; ++l)
        r8[l] = __fadd_rn(r8[l], __fmul_rn(sx[i + l], sx[i + l]));
    }
    sx2s = __fadd_rn(__fadd_rn(__fadd_rn(r8[0], r8[1]), __fadd_rn(r8[2], r8[3])),
                     __fadd_rn(__fadd_rn(r8[4], r8[5]), __fadd_rn(r8[6], r8[7])));
  }
  __syncthreads();
  const float x2 = sx2s;

  float bd = 3.4e38f;
  int   bi = KBINS;
#pragma unroll 2
  for (int jj = 0; jj < KBINS / 256; ++jj) {   // 8 codes/thread, ascending
    int j = jj * 256 + tid;
    const float* kr = kg + j * WDIM;
    float c = 0.f;
#pragma unroll
    for (int w = 0; w < WDIM; ++w)
      c = __fmaf_rn(sx[w], kr[w], c);
    float d = __fadd_rn(__fsub_rn(x2, __fmul_rn(2.0f, c)), k2g[j]);
    if (d < bd) { bd = d; bi = j; }
  }
  sd[tid] = bd;
  si[tid] = bi;
  __syncthreads();

  for (int off = 128; off > 0; off >>= 1) {
    if (tid < off) {
      float od = sd[tid + off];
      int   oi = si[tid + off];
      if (od < sd[tid] || (od == sd[tid] && oi < si[tid])) {
        sd[tid] = od;
        si[tid] = oi;
      }
    }
    __syncthreads();
  }
  const int bj = si[0];
  if (tid == 0) out[XL_OFF + row] = (float)bj;
  if (tid < WDIM)
    out[XD_OFF + (size_t)n * WDIM * TDIM + (size_t)tid * TDIM + t] = kg[bj * WDIM + tid];
}

__global__ void finalize_kernel(const double* __restrict__ wsd, float* __restrict__ out) {
  if (threadIdx.x == 0) {
    double size = (double)XSIZE;
    double commit = wsd[2] / size;
    double fit = wsd[3] / (double)NROWS;
    double mean = wsd[0] / size;
    double var = wsd[1] / size - mean * mean;
    if (var < 0.0) var = 0.0;
    out[SCAL_OFF + 0] = (float)commit;
    out[SCAL_OFF + 1] = (float)fit;
    out[SCAL_OFF + 2] = (float)sqrt(var);
  }
}

extern "C" void kernel_launch(void* const* d_in, const int* in_sizes, int n_in,
                              void* d_out, int out_size, void* d_ws, size_t ws_size,
                              hipStream_t stream) {
  const float* x = (const float*)d_in[0];
  const float* kg = (const float*)d_in[1];
  float* out = (float*)d_out;
  double* wsd = (double*)d_ws;
  float* k2  = (float*)((char*)d_ws + WS_K2_OFF);
  int* cnt   = (int*)((char*)d_ws + WS_CNT_OFF);
  int* flags = (int*)((char*)d_ws + WS_FLAG_OFF);
  short* khi = (short*)((char*)d_ws + WS_KHI_OFF);
  short* klo = (short*)((char*)d_ws + WS_KLO_OFF);

  hipLaunchKernelGGL(prep_kernel, dim3(KBINS / 256), dim3(256), 0, stream,
                     kg, k2, khi, klo, wsd, cnt);
  hipLaunchKernelGGL(vq_mfma, dim3(NROWS / MT), dim3(256), 0, stream,
                     x, kg, k2, khi, klo, out, wsd, cnt, flags);
  hipLaunchKernelGGL(recheck_np, dim3(MAXFLAG), dim3(256), 0, stream,
                     x, kg, k2, cnt, flags, out);
  hipLaunchKernelGGL(finalize_kernel, dim3(1), dim3(1), 0, stream, wsd, out);
}